// Round 5
// baseline (1498.054 us; speedup 1.0000x reference)
//
#include <hip/hip_runtime.h>

#define TT 2048
#define FF 12
#define HH 96
#define NG 384
#define CK 64
#define NT 768
#define L2E 1.44269504088896340736f

typedef __attribute__((ext_vector_type(2))) float f2;
typedef __attribute__((ext_vector_type(4))) float f4;

__device__ __forceinline__ float fast_exp2(float x){ return __builtin_amdgcn_exp2f(x); }
__device__ __forceinline__ float fast_rcp(float x){ return __builtin_amdgcn_rcpf(x); }
__device__ __forceinline__ float sigm(float x){
  return fast_rcp(1.f + fast_exp2(-L2E * x));
}
__device__ __forceinline__ float tanh_f(float x){
  const float e = fast_exp2((-2.f*L2E)*fabsf(x));
  return copysignf((1.f - e) * fast_rcp(1.f + e), x);
}

// One block per batch element. 12 waves = 3 row-groups x 4 K-slices (24 floats).
// Per step: phase A (all waves): 2 rows x 24 MACs vs wave-uniform h-slice
// (6 broadcast ds_read_b128), partials to LDS (stride-5, conflict-free).
// phase B (96 threads): reduce 4 slices x 4 gates + PC, activate, c/h update.
// 2 barriers/step. x-part precomputed per 64-step chunk into PC (no recurrence).
__global__ __launch_bounds__(NT, 3) void lstm_persist(
  const float* __restrict__ seq, const int* __restrict__ ev, const int* __restrict__ rsi,
  const int* __restrict__ len, const float* __restrict__ eemb, const float* __restrict__ remb,
  const float* __restrict__ W_ih, const float* __restrict__ W_hh,
  const float* __restrict__ b_ih, const float* __restrict__ b_hh,
  const float* __restrict__ W_mlp, const float* __restrict__ b_mlp,
  const float* __restrict__ W_fc, const float* __restrict__ b_fc,
  float* __restrict__ out)
{
  const int b   = blockIdx.x;
  const int tid = threadIdx.x;
  const int w   = tid >> 6;
  const int l   = tid & 63;
  const int s   = w & 3;            // K-slice: h[24s, 24s+24)
  const int gg  = w >> 2;           // row group: rows [128gg, 128gg+128)
  const int r0  = 128*gg + l;       // this lane: rows r0, r0+64

  __shared__ __align__(16) float hbuf[2][HH];
  __shared__ __align__(16) float part[NG*5];
  __shared__ __align__(16) float PC[CK*NG];
  __shared__ __align__(16) float xst[CK*24];
  __shared__ __align__(16) float lastk[3*HH];
  __shared__ __align__(16) float tmp[192];
  __shared__ __align__(16) float h2[2*HH];
  __shared__ __align__(16) float et[32*6];
  __shared__ __align__(16) float rt[8*3];
  __shared__ int evb[CK];
  __shared__ int rsb[CK];

  // ---- prologue: phase-A weight slices (2 rows x 24 floats, as f2 pairs) ----
  f2 wa[24];
  {
    const float* p0 = W_hh + (size_t)r0*96 + 24*s;
    const float* p1 = W_hh + (size_t)(r0+64)*96 + 24*s;
    #pragma unroll
    for (int j = 0; j < 6; ++j) {
      const f4 q0 = ((const f4*)p0)[j];
      const f4 q1 = ((const f4*)p1)[j];
      wa[2*j]    = q0.xy;  wa[2*j+1]  = q0.zw;
      wa[12+2*j] = q1.xy;  wa[13+2*j] = q1.zw;
    }
  }
  // ---- prep weights: W_ih row (21 + 3 zero-pad) per thread ----
  // NT = 2*NG exactly; NG is NOT a power of two -> no bitmask here.
  const int th2 = (tid >= NG) ? 1 : 0;     // time-row parity this thread handles
  const int gB  = tid - th2*NG;            // gate row 0..383
  f2 wi2[12];
  {
    float wi[24];
    #pragma unroll
    for (int k = 0; k < 21; ++k) wi[k] = W_ih[gB*21 + k];
    wi[21] = wi[22] = wi[23] = 0.f;
    #pragma unroll
    for (int j = 0; j < 12; ++j) wi2[j] = (f2){wi[2*j], wi[2*j+1]};
  }
  const float bgB = b_ih[gB] + b_hh[gB];

  for (int i = tid; i < 2*HH; i += NT) ((float*)hbuf)[i] = 0.f;
  for (int i = tid; i < 3*HH; i += NT) lastk[i] = 0.f;
  for (int i = tid; i < 192;  i += NT) et[i] = eemb[i];
  for (int i = tid; i < 24;   i += NT) rt[i] = remb[i];

  float c_state = 0.f;
  const int L  = len[b];
  const int ht = tid;                       // phase-B h index (tid < 96)

  for (int t = 0; t < L; ++t) {
    const int cr = t & (CK-1);
    if (cr == 0) {
      // ---- chunk prep: stage seq, embed, compute PC[0..63][384] ----
      {
        const int r = tid / 12, c = tid - r*12;
        xst[r*24 + c] = seq[(size_t)b*(TT*FF) + (size_t)t*FF + tid];
        if (tid < CK) {
          evb[tid] = ev [b*TT + t + tid];
          rsb[tid] = rsi[b*TT + t + tid];
        }
      }
      __syncthreads();
      {
        const int r = tid / 12, c2 = tid - r*12 + 12;
        float val;
        if (c2 < 18)      val = et[evb[r]*6 + (c2-12)];
        else if (c2 < 21) val = rt[rsb[r]*3 + (c2-18)];
        else              val = 0.f;
        xst[r*24 + c2] = val;
      }
      __syncthreads();
      {
        #pragma unroll 4
        for (int jj = 0; jj < CK/2; ++jj) {
          const int tr = 2*jj + th2;
          const f4* xp = (const f4*)(xst + tr*24);
          f2 a = (f2){0.f, 0.f};
          #pragma unroll
          for (int j2 = 0; j2 < 6; ++j2) {
            const f4 q = xp[j2];
            a = wi2[2*j2]   * q.xy + a;
            a = wi2[2*j2+1] * q.zw + a;
          }
          PC[tr*NG + gB] = bgB + a.x + a.y;
        }
      }
      __syncthreads();
    }

    // ---- phase A: partial dots vs wave-uniform h slice ----
    {
      const f4* hq = (const f4*)(hbuf[t & 1] + 24*s);
      const f4 q0=hq[0], q1=hq[1], q2=hq[2], q3=hq[3], q4=hq[4], q5=hq[5];
      f2 aA=(f2){0,0}, aB=(f2){0,0}, aC=(f2){0,0}, aD=(f2){0,0};
      aA = wa[0] *q0.xy + aA;  aB = wa[1] *q0.zw + aB;
      aC = wa[12]*q0.xy + aC;  aD = wa[13]*q0.zw + aD;
      aA = wa[2] *q1.xy + aA;  aB = wa[3] *q1.zw + aB;
      aC = wa[14]*q1.xy + aC;  aD = wa[15]*q1.zw + aD;
      aA = wa[4] *q2.xy + aA;  aB = wa[5] *q2.zw + aB;
      aC = wa[16]*q2.xy + aC;  aD = wa[17]*q2.zw + aD;
      aA = wa[6] *q3.xy + aA;  aB = wa[7] *q3.zw + aB;
      aC = wa[18]*q3.xy + aC;  aD = wa[19]*q3.zw + aD;
      aA = wa[8] *q4.xy + aA;  aB = wa[9] *q4.zw + aB;
      aC = wa[20]*q4.xy + aC;  aD = wa[21]*q4.zw + aD;
      aA = wa[10]*q5.xy + aA;  aB = wa[11]*q5.zw + aB;
      aC = wa[22]*q5.xy + aC;  aD = wa[23]*q5.zw + aD;
      part[r0*5 + s]      = aA.x + aA.y + aB.x + aB.y;
      part[(r0+64)*5 + s] = aC.x + aC.y + aD.x + aD.y;
    }
    __syncthreads();

    // ---- phase B: reduce + activate + c/h update (96 threads) ----
    if (tid < HH) {
      float gv[4];
      #pragma unroll
      for (int gt = 0; gt < 4; ++gt) {
        const int rr = gt*96 + ht;
        const float* pp = part + rr*5;
        gv[gt] = (pp[0] + pp[1]) + (pp[2] + pp[3]) + PC[cr*NG + rr];
      }
      const float gi = sigm(gv[0]);
      const float gf = sigm(gv[1]);
      const float gG = tanh_f(gv[2]);
      const float go = sigm(gv[3]);
      c_state = fmaf(gf, c_state, gi*gG);
      const float hn = go * tanh_f(c_state);
      hbuf[(t+1) & 1][ht] = hn;
      const int kk = t + 3 - L;
      if (kk >= 0) lastk[kk*96 + ht] = hn;
    }
    __syncthreads();
  }

  // ---- epilogue ----
  const float* hfin = hbuf[L & 1];
  if (tid < 192) {
    const int hh = tid / 96;
    const int m  = tid - hh*96;
    const float* wp = W_mlp + m*288 + hh*144;
    const float* xp = lastk + hh*144;
    float sacc = 0.f;
    #pragma unroll 8
    for (int i = 0; i < 144; ++i) sacc = fmaf(wp[i], xp[i], sacc);
    tmp[tid] = sacc;
  }
  __syncthreads();
  if (tid < 96) {
    const float hl = tmp[tid] + tmp[96+tid] + b_mlp[tid];
    h2[96 + tid] = fmaxf(hl, 0.f);
    h2[tid] = hfin[tid];
  }
  __syncthreads();
  if (tid < 128) {
    const int o  = tid >> 6;
    const int ll = tid & 63;
    const float* wf = W_fc + o*192 + 3*ll;
    float sv = fmaf(wf[0], h2[3*ll+0], fmaf(wf[1], h2[3*ll+1], wf[2]*h2[3*ll+2]));
    #pragma unroll
    for (int off = 32; off > 0; off >>= 1) sv += __shfl_down(sv, off);
    if (ll == 0) out[b*2 + o] = sv + b_fc[o];
  }
}

extern "C" void kernel_launch(void* const* d_in, const int* in_sizes, int n_in,
                              void* d_out, int out_size, void* d_ws, size_t ws_size,
                              hipStream_t stream) {
  const float* seq   = (const float*)d_in[0];
  const int*   ev    = (const int*)  d_in[1];
  const int*   rsi   = (const int*)  d_in[2];
  const int*   len   = (const int*)  d_in[3];
  const float* eemb  = (const float*)d_in[4];
  const float* remb  = (const float*)d_in[5];
  const float* W_ih  = (const float*)d_in[6];
  const float* W_hh  = (const float*)d_in[7];
  const float* b_ih  = (const float*)d_in[8];
  const float* b_hh  = (const float*)d_in[9];
  const float* W_mlp = (const float*)d_in[10];
  const float* b_mlp = (const float*)d_in[11];
  const float* W_fc  = (const float*)d_in[12];
  const float* b_fc  = (const float*)d_in[13];

  hipLaunchKernelGGL(lstm_persist, dim3(256), dim3(NT), 0, stream,
                     seq, ev, rsi, len, eemb, remb, W_ih, W_hh, b_ih, b_hh,
                     W_mlp, b_mlp, W_fc, b_fc, (float*)d_out);
}

// Round 6
// 1459.745 us; speedup vs baseline: 1.0262x; 1.0262x over previous
//
#include <hip/hip_runtime.h>

#define TT 2048
#define FF 12
#define HH 96
#define NG 384
#define CK 64
#define NT 384
#define L2E 1.44269504088896340736f

typedef __attribute__((ext_vector_type(2))) float f2;
typedef __attribute__((ext_vector_type(4))) float f4;

__device__ __forceinline__ float fast_exp2(float x){ return __builtin_amdgcn_exp2f(x); }
__device__ __forceinline__ float fast_rcp(float x){ return __builtin_amdgcn_rcpf(x); }
__device__ __forceinline__ float sigm(float x){ return fast_rcp(1.f + fast_exp2(-L2E*x)); }
__device__ __forceinline__ float tanh_f(float x){
  const float e = fast_exp2((-2.f*L2E)*fabsf(x));
  return copysignf((1.f - e)*fast_rcp(1.f + e), x);
}
// sum across the 4 lanes of a hardware quad via DPP quad_perm (pure VALU, no LDS)
__device__ __forceinline__ float quad_sum(float x){
  int y1 = __builtin_amdgcn_update_dpp(0, __float_as_int(x), 0xB1, 0xF, 0xF, true); // xor 1
  float s = x + __int_as_float(y1);
  int y2 = __builtin_amdgcn_update_dpp(0, __float_as_int(s), 0x4E, 0xF, 0xF, true); // xor 2
  return s + __int_as_float(y2);
}

// One block per batch element, 384 threads (6 waves).
// Quad q (lanes 4q..4q+3) owns h-index j=q: lane p holds W_hh rows
// {j, 96+j, 192+j, 288+j} x K-quarter [24p,24p+24) in 96 VGPRs.
// Per step: 6x ds_read_b128 h-slice -> 48 pk_fma -> DPP quad reduce (VALU) ->
// redundant activation/c/h per lane -> p==0 writes h[j] -> ONE barrier.
// x-contribution PC[t][row] precomputed per 64-step chunk (no recurrence).
__global__ __launch_bounds__(NT, 2) void lstm_persist(
  const float* __restrict__ seq, const int* __restrict__ ev, const int* __restrict__ rsi,
  const int* __restrict__ len, const float* __restrict__ eemb, const float* __restrict__ remb,
  const float* __restrict__ W_ih, const float* __restrict__ W_hh,
  const float* __restrict__ b_ih, const float* __restrict__ b_hh,
  const float* __restrict__ W_mlp, const float* __restrict__ b_mlp,
  const float* __restrict__ W_fc, const float* __restrict__ b_fc,
  float* __restrict__ out)
{
  const int b   = blockIdx.x;
  const int tid = threadIdx.x;
  const int j   = tid >> 2;        // h index 0..95
  const int p   = tid & 3;         // K quarter

  __shared__ __align__(16) float hbuf[2][HH];
  __shared__ __align__(16) float PC[CK*NG];
  __shared__ __align__(16) float xst[CK*24];
  __shared__ __align__(16) float lastk[3*HH];
  __shared__ __align__(16) float tmp[192];
  __shared__ __align__(16) float h2[2*HH];
  __shared__ __align__(16) float et[32*6];
  __shared__ __align__(16) float rt[8*3];
  __shared__ int evb[CK];
  __shared__ int rsb[CK];

  // ---- per-lane recurrent weights: 4 gate rows x 24-float K-quarter ----
  f2 wr[48];                       // [gate*12 + 2*q6 (+1)]
  #pragma unroll
  for (int gt = 0; gt < 4; ++gt) {
    const float* pw = W_hh + (size_t)(gt*96 + j)*96 + 24*p;
    #pragma unroll
    for (int q6 = 0; q6 < 6; ++q6) {
      const f4 qq = ((const f4*)pw)[q6];
      wr[gt*12 + 2*q6]     = qq.xy;
      wr[gt*12 + 2*q6 + 1] = qq.zw;
    }
  }
  // ---- PC weights: thread tid owns gate row tid (NT == NG) ----
  f2 wi2[12];
  {
    float wi[24];
    #pragma unroll
    for (int k = 0; k < 21; ++k) wi[k] = W_ih[tid*21 + k];
    wi[21] = wi[22] = wi[23] = 0.f;
    #pragma unroll
    for (int q6 = 0; q6 < 12; ++q6) wi2[q6] = (f2){wi[2*q6], wi[2*q6+1]};
  }
  const float bgB = b_ih[tid] + b_hh[tid];

  for (int i = tid; i < 2*HH; i += NT) ((float*)hbuf)[i] = 0.f;
  for (int i = tid; i < 3*HH; i += NT) lastk[i] = 0.f;
  for (int i = tid; i < 192;  i += NT) et[i] = eemb[i];
  for (int i = tid; i < 24;   i += NT) rt[i] = remb[i];

  float c_state = 0.f;
  const int L = len[b];

  for (int t = 0; t < L; ++t) {
    const int cr = t & (CK-1);
    if (cr == 0) {
      // ---- chunk prep: stage x, then PC[tr][row] = W_ih.x_tr + b ----
      for (int q = tid; q < CK*FF; q += NT) {
        const int r = q / 12, c = q - r*12;
        xst[r*24 + c] = seq[(size_t)b*(TT*FF) + (size_t)t*FF + q];
      }
      if (tid < CK) {
        evb[tid] = ev [b*TT + t + tid];
        rsb[tid] = rsi[b*TT + t + tid];
      }
      __syncthreads();
      for (int q = tid; q < CK*12; q += NT) {
        const int r = q / 12, c2 = q - r*12 + 12;
        float val;
        if (c2 < 18)      val = et[evb[r]*6 + (c2-12)];
        else if (c2 < 21) val = rt[rsb[r]*3 + (c2-18)];
        else              val = 0.f;
        xst[r*24 + c2] = val;
      }
      __syncthreads();
      #pragma unroll 4
      for (int tr = 0; tr < CK; ++tr) {
        const f4* xp = (const f4*)(xst + tr*24);
        f2 a = (f2){0.f, 0.f};
        #pragma unroll
        for (int q6 = 0; q6 < 6; ++q6) {
          const f4 qq = xp[q6];
          a = wi2[2*q6]   * qq.xy + a;
          a = wi2[2*q6+1] * qq.zw + a;
        }
        PC[tr*NG + tid] = bgB + a.x + a.y;
      }
      __syncthreads();
    }

    // ---- one-phase step ----
    const float* hb = hbuf[t & 1];
    const f4* hq = (const f4*)(hb + 24*p);
    f4 hv[6];
    #pragma unroll
    for (int q6 = 0; q6 < 6; ++q6) hv[q6] = hq[q6];
    const float pci = PC[cr*NG +        j];
    const float pcf = PC[cr*NG +  96  + j];
    const float pcg = PC[cr*NG + 192  + j];
    const float pco = PC[cr*NG + 288  + j];

    f2 ai=(f2){0,0}, af=(f2){0,0}, ag=(f2){0,0}, ao=(f2){0,0};
    #pragma unroll
    for (int q6 = 0; q6 < 6; ++q6) {
      const f4 qq = hv[q6];
      ai = wr[     2*q6]*qq.xy + ai;  ai = wr[     2*q6+1]*qq.zw + ai;
      af = wr[12 + 2*q6]*qq.xy + af;  af = wr[12 + 2*q6+1]*qq.zw + af;
      ag = wr[24 + 2*q6]*qq.xy + ag;  ag = wr[24 + 2*q6+1]*qq.zw + ag;
      ao = wr[36 + 2*q6]*qq.xy + ao;  ao = wr[36 + 2*q6+1]*qq.zw + ao;
    }
    const float si = quad_sum(ai.x + ai.y) + pci;
    const float sf = quad_sum(af.x + af.y) + pcf;
    const float sg = quad_sum(ag.x + ag.y) + pcg;
    const float so = quad_sum(ao.x + ao.y) + pco;

    const float gi = sigm(si);
    const float gf = sigm(sf);
    const float gG = tanh_f(sg);
    const float go = sigm(so);
    c_state = fmaf(gf, c_state, gi*gG);        // identical copy in all 4 quad lanes
    const float hn = go * tanh_f(c_state);

    if (p == 0) {
      hbuf[(t+1) & 1][j] = hn;
      const int kk = t + 3 - L;
      if (kk >= 0) lastk[kk*96 + j] = hn;
    }
    __syncthreads();                            // ONE barrier per step
  }

  // ---- epilogue ----
  const float* hfin = hbuf[L & 1];
  if (tid < 192) {
    const int hh = tid / 96;
    const int m  = tid - hh*96;
    const float* wp = W_mlp + m*288 + hh*144;
    const float* xp = lastk + hh*144;
    float sacc = 0.f;
    #pragma unroll 8
    for (int i = 0; i < 144; ++i) sacc = fmaf(wp[i], xp[i], sacc);
    tmp[tid] = sacc;
  }
  __syncthreads();
  if (tid < 96) {
    const float hl = tmp[tid] + tmp[96+tid] + b_mlp[tid];
    h2[96 + tid] = fmaxf(hl, 0.f);
    h2[tid] = hfin[tid];
  }
  __syncthreads();
  if (tid < 128) {
    const int o  = tid >> 6;
    const int ll = tid & 63;
    const float* wf = W_fc + o*192 + 3*ll;
    float sv = fmaf(wf[0], h2[3*ll+0], fmaf(wf[1], h2[3*ll+1], wf[2]*h2[3*ll+2]));
    #pragma unroll
    for (int off = 32; off > 0; off >>= 1) sv += __shfl_down(sv, off);
    if (ll == 0) out[b*2 + o] = sv + b_fc[o];
  }
}

extern "C" void kernel_launch(void* const* d_in, const int* in_sizes, int n_in,
                              void* d_out, int out_size, void* d_ws, size_t ws_size,
                              hipStream_t stream) {
  const float* seq   = (const float*)d_in[0];
  const int*   ev    = (const int*)  d_in[1];
  const int*   rsi   = (const int*)  d_in[2];
  const int*   len   = (const int*)  d_in[3];
  const float* eemb  = (const float*)d_in[4];
  const float* remb  = (const float*)d_in[5];
  const float* W_ih  = (const float*)d_in[6];
  const float* W_hh  = (const float*)d_in[7];
  const float* b_ih  = (const float*)d_in[8];
  const float* b_hh  = (const float*)d_in[9];
  const float* W_mlp = (const float*)d_in[10];
  const float* b_mlp = (const float*)d_in[11];
  const float* W_fc  = (const float*)d_in[12];
  const float* b_fc  = (const float*)d_in[13];

  hipLaunchKernelGGL(lstm_persist, dim3(256), dim3(NT), 0, stream,
                     seq, ev, rsi, len, eemb, remb, W_ih, W_hh, b_ih, b_hh,
                     W_mlp, b_mlp, W_fc, b_fc, (float*)d_out);
}